// Round 8
// baseline (777.567 us; speedup 1.0000x reference)
//
#include <hip/hip_runtime.h>
#include <hip/hip_bf16.h>

// ---------- types ----------
typedef __bf16 bf16x8 __attribute__((ext_vector_type(8)));
typedef float  f32x4  __attribute__((ext_vector_type(4)));

#define H_DIM 112
#define W_DIM 112
#define CIN 64
#define CMID 192          // 3*64
#define COUT 128
#define NB 16

// ---------------------------------------------------------------
// Kernel A: repack weights [co][ci][kh][kw] fp32 -> [khw][co][ci] bf16
// ci is the y-channel index: ci = p*64 + c  (power-major, matching the
// fused kernel's LDS half-row layout).
// ---------------------------------------------------------------
__global__ __launch_bounds__(256) void repack_w_kernel(
    const float* __restrict__ w, __hip_bfloat16* __restrict__ wr)
{
    int idx = blockIdx.x * 256 + threadIdx.x;
    if (idx < 9 * COUT * CMID) {
        int ci  = idx % CMID;
        int t   = idx / CMID;
        int co  = t % COUT;
        int khw = t / COUT;
        wr[idx] = __float2bfloat16(w[(co * CMID + ci) * 9 + khw]);
    }
}

// ---------------------------------------------------------------
// FUSED Kernel: bilinear-shift + Maclaurin powers computed IN-KERNEL into
// the conv's double-buffered LDS half-rows (no y tensor, no shift_pow
// kernel, no global_load_lds). Per step (kh, half) the block computes
// y[row=h+kh-1][px][half*96..+95] directly from x:
//   thread (cc=tid&63, pg=tid>>6) computes v = bilinear(x[n][cc], row, px)
//   for px = pg*28..+27 and writes the powers this half needs:
//     half0: elem cc      = v        (p0 c0..63)
//            elem 64+cc   = v^2      (p1 c0..31, cc<32)
//     half1: elem cc-32   = v^2      (p1 c32..63, cc>=32)
//            elem 32+cc   = v^3      (p2 c0..63)
//   (y channel = p*64+c; half = 96-channel groups -- same layout the DMA
//    staged before, verified R0-R7; bilinear math verbatim from the
//    PASSING round-7 shift_pow.)
// Step order per iteration: (1) compute step s+1 into buf^1 (VMEM taps
// consumed by VALU, ds_write_b16), (2) af weight loads, (3) SGB-pinned
// ds_read/MFMA pipeline on buf (round-4 structure, 133us verified),
// (4) one barrier. Compute instructions are unpinned -> scheduler
// interleaves them into MFMA idle cycles (VALU was 11% busy).
// MFMA-pipe floor ~43 us.
// ---------------------------------------------------------------
#define YSTR_E 104                  // elements per px slot (208 B)
#define YLDS_E (114 * 104)          // 11,856 elems = 23,712 B per buffer

// bilinear compute of one (row, half) half-row into dst (LDS).
__device__ __forceinline__ void compute_half(
    int row, int half, __bf16* dstb, const float* bx,
    int ix, int iy, float wx, float wy, int cc, int pg)
{
    int r0 = row + iy, r1 = r0 + 1;
    float vy0 = ((unsigned)r0 < (unsigned)H_DIM) ? 1.f : 0.f;
    float vy1 = ((unsigned)r1 < (unsigned)H_DIM) ? 1.f : 0.f;
    float omwx = 1.f - wx, omwy = 1.f - wy;
    float ww00 = omwy * omwx * vy0;
    float ww01 = omwy * wx   * vy0;
    float ww10 = wy * omwx * vy1;
    float ww11 = wy * wx   * vy1;
    const float* row0 = bx + min(max(r0, 0), H_DIM - 1) * W_DIM;
    const float* row1 = bx + min(max(r1, 0), H_DIM - 1) * W_DIM;
    __hip_bfloat16* dst = (__hip_bfloat16*)dstb;

    if (half == 0) {
        #pragma unroll 7
        for (int p = 0; p < 28; ++p) {
            int px = pg * 28 + p;
            int q0 = px + ix, q1 = q0 + 1;
            float f0 = ((unsigned)q0 < (unsigned)W_DIM) ? 1.f : 0.f;
            float f1 = ((unsigned)q1 < (unsigned)W_DIM) ? 1.f : 0.f;
            int a0 = min(max(q0, 0), W_DIM - 1);
            int a1 = min(max(q1, 0), W_DIM - 1);
            float v = f0 * (ww00 * row0[a0] + ww10 * row1[a0])
                    + f1 * (ww01 * row0[a1] + ww11 * row1[a1]);
            __hip_bfloat16* bp = dst + (px + 1) * YSTR_E;
            bp[cc] = __float2bfloat16(v);
            if (cc < 32) bp[64 + cc] = __float2bfloat16(v * v);
        }
    } else {
        #pragma unroll 7
        for (int p = 0; p < 28; ++p) {
            int px = pg * 28 + p;
            int q0 = px + ix, q1 = q0 + 1;
            float f0 = ((unsigned)q0 < (unsigned)W_DIM) ? 1.f : 0.f;
            float f1 = ((unsigned)q1 < (unsigned)W_DIM) ? 1.f : 0.f;
            int a0 = min(max(q0, 0), W_DIM - 1);
            int a1 = min(max(q1, 0), W_DIM - 1);
            float v = f0 * (ww00 * row0[a0] + ww10 * row1[a0])
                    + f1 * (ww01 * row0[a1] + ww11 * row1[a1]);
            float v2 = v * v;
            __hip_bfloat16* bp = dst + (px + 1) * YSTR_E;
            if (cc >= 32) bp[cc - 32] = __float2bfloat16(v2);
            bp[32 + cc] = __float2bfloat16(v2 * v);
        }
    }
}

#define CONV_GROUP(G, CUR, NXT) do {                                          \
    const int c3_ = (G) / 3, kw_ = (G) % 3;                                   \
    if ((G) < 8) {                                                            \
        const int c3n_ = ((G) + 1) / 3, kwn_ = ((G) + 1) % 3;                 \
        _Pragma("unroll")                                                     \
        for (int nt = 0; nt < 7; ++nt)                                        \
            NXT[nt] = *(const bf16x8*)(lbase +                                \
                (nt * 16 + kwn_) * YSTR_E + c3n_ * 32);                       \
    }                                                                         \
    _Pragma("unroll")                                                         \
    for (int nt = 0; nt < 7; ++nt) {                                          \
        acc[0][nt] = __builtin_amdgcn_mfma_f32_16x16x32_bf16(                 \
            af[c3_][kw_][0], CUR[nt], acc[0][nt], 0, 0, 0);                   \
        acc[1][nt] = __builtin_amdgcn_mfma_f32_16x16x32_bf16(                 \
            af[c3_][kw_][1], CUR[nt], acc[1][nt], 0, 0, 0);                   \
    }                                                                         \
    if ((G) < 8) {                                                            \
        _Pragma("unroll")                                                     \
        for (int k_ = 0; k_ < 7; ++k_) {                                      \
            __builtin_amdgcn_sched_group_barrier(0x100, 1, 0); /* DS_READ */  \
            __builtin_amdgcn_sched_group_barrier(0x008, 2, 0); /* MFMA   */   \
        }                                                                     \
    } else {                                                                  \
        __builtin_amdgcn_sched_group_barrier(0x008, 14, 0);                   \
    }                                                                         \
} while (0)

__global__ __launch_bounds__(256, 2) void conv_kernel(
    const float* __restrict__ x,     // [16][64][112][112]
    const __bf16* __restrict__ wr,   // [9][128][192]
    const float* __restrict__ bias,
    const float* __restrict__ shifts,
    float* __restrict__ out)         // [16][128][112][112]
{
    __shared__ __align__(16) __bf16 ybuf[2][YLDS_E];   // 47,424 B

    const int tid  = threadIdx.x;
    const int lane = tid & 63;
    const int wid  = tid >> 6;
    const int m    = lane & 15;
    const int quad = lane >> 4;

    // XCD-chunked swizzle: grid 1792 = 8 XCDs x 224; consecutive ids within
    // a chunk are consecutive h (same n) -> x-row/L2 reuse stays on one XCD.
    const int bid = blockIdx.x;
    const int id  = (bid & 7) * 224 + (bid >> 3);
    const int n   = id / H_DIM;
    const int h   = id - n * H_DIM;

    // compute-role params: channel cc, px group pg
    const int cc = tid & 63;
    const int pg = tid >> 6;
    const float sx = shifts[2 * cc]     * 4.0f;
    const float sy = shifts[2 * cc + 1] * 4.0f;
    const float fxf = floorf(sx), fyf = floorf(sy);
    const int   ix = (int)fxf,    iy = (int)fyf;
    const float wxp = sx - fxf,   wyp = sy - fyf;
    const float* bx = x + (size_t)(n * CIN + cc) * (H_DIM * W_DIM);

    // zero halo slots (slot 0 = px -1, slot 113 = px 112) of both buffers
    if (tid < 208) {
        int b    = tid >= 104;
        int r    = tid - b * 104;
        int slot = (r >= 52) ? 113 : 0;
        int dw   = (r >= 52) ? r - 52 : r;
        ((unsigned*)&ybuf[b][0])[slot * 52 + dw] = 0u;
    }

    f32x4 acc[2][7];
    #pragma unroll
    for (int mt = 0; mt < 2; ++mt)
        #pragma unroll
        for (int nt = 0; nt < 7; ++nt)
            #pragma unroll
            for (int r = 0; r < 4; ++r) acc[mt][nt][r] = 0.0f;

    // step s: kh = s>>1 (row h+kh-1), half = s&1 (channels half*96 ..)
    const int f = (h == 0)         ? 2 : 0;
    const int l = (h == H_DIM - 1) ? 3 : 5;

    // ---- prologue: compute step f into buffer 0 ----
    compute_half(h + (f >> 1) - 1, f & 1, &ybuf[0][0],
                 bx, ix, iy, wxp, wyp, cc, pg);
    __syncthreads();

    int buf = 0;
    for (int s = f; s <= l; ++s) {
        // ---- (1) compute step s+1 into the other buffer ----
        if (s < l) {
            compute_half(h + ((s + 1) >> 1) - 1, (s + 1) & 1,
                         &ybuf[buf ^ 1][0], bx, ix, iy, wxp, wyp, cc, pg);
        }

        // ---- (2) af weight loads for step s ----
        const int kh = s >> 1, half = s & 1;
        bf16x8 af[3][3][2];
        #pragma unroll
        for (int c3 = 0; c3 < 3; ++c3)
            #pragma unroll
            for (int kw = 0; kw < 3; ++kw)
                #pragma unroll
                for (int mt = 0; mt < 2; ++mt)
                    af[c3][kw][mt] = *(const bf16x8*)(
                        wr + (size_t)((kh * 3 + kw) * COUT + wid * 32 + mt * 16 + m) * CMID
                           + half * 96 + c3 * 32 + quad * 8);

        // ---- (3) MFMA pipeline on ybuf[buf] (round-4 structure) ----
        const __bf16* lbase = &ybuf[buf][m * YSTR_E + quad * 8];

        bf16x8 bA[7], bB[7];
        #pragma unroll
        for (int nt = 0; nt < 7; ++nt)
            bA[nt] = *(const bf16x8*)(lbase + (nt * 16 + 0) * YSTR_E + 0 * 32);
        __builtin_amdgcn_sched_group_barrier(0x100, 7, 0);   // 7x DS_READ

        CONV_GROUP(0, bA, bB);
        CONV_GROUP(1, bB, bA);
        CONV_GROUP(2, bA, bB);
        CONV_GROUP(3, bB, bA);
        CONV_GROUP(4, bA, bB);
        CONV_GROUP(5, bB, bA);
        CONV_GROUP(6, bA, bB);
        CONV_GROUP(7, bB, bA);
        CONV_GROUP(8, bA, bB);

        __syncthreads();   // step-s reads done + step-(s+1) writes visible
        buf ^= 1;
    }

    // epilogue: D col = px (lane&15), row = quad*4+r -> co
    #pragma unroll
    for (int mt = 0; mt < 2; ++mt) {
        const int co0 = wid * 32 + mt * 16 + quad * 4;
        float bv[4];
        #pragma unroll
        for (int rr = 0; rr < 4; ++rr) bv[rr] = bias[co0 + rr];
        #pragma unroll
        for (int nt = 0; nt < 7; ++nt) {
            int j = nt * 16 + m;
            #pragma unroll
            for (int rr = 0; rr < 4; ++rr) {
                out[(((size_t)n * COUT + co0 + rr) * H_DIM + h) * W_DIM + j] =
                    acc[mt][nt][rr] + bv[rr];
            }
        }
    }
}

// ---------------------------------------------------------------
extern "C" void kernel_launch(void* const* d_in, const int* in_sizes, int n_in,
                              void* d_out, int out_size, void* d_ws, size_t ws_size,
                              hipStream_t stream) {
    const float* x      = (const float*)d_in[0];
    const float* w      = (const float*)d_in[1];
    const float* bias   = (const float*)d_in[2];
    const float* shifts = (const float*)d_in[3];
    float* out = (float*)d_out;

    __hip_bfloat16* wr = (__hip_bfloat16*)d_ws;   // 442,368 B

    repack_w_kernel<<<dim3((9 * COUT * CMID + 255) / 256), 256, 0, stream>>>(w, wr);
    conv_kernel<<<dim3(H_DIM * NB), 256, 0, stream>>>(
        x, (const __bf16*)wr, bias, shifts, out);
}